// Round 7
// baseline (130.373 us; speedup 1.0000x reference)
//
#include <hip/hip_runtime.h>
#include <hip/hip_bf16.h>
#include <math.h>

// VariableSelectionNetwork — MI355X (gfx950), round 7
//
// Identity 1: scorer LayerNorm over a size-1 axis => output == sc_ln_b, so
// softmax weights W[f] = softmax(sc_ln_b) are constant and the scorer GRN is
// dead code.
// Identity 2 (new): gate logit = h2 @ gate^T + gb = h1 @ (gate_w fc2_w)^T +
// (gate_w fc2_b + gb). Precompute GF = gate_w @ fc2_w in prep => FC2 and GATE
// both consume h1 and fuse into ONE GEMM phase.
//
// Round 7 = round-5 winner (T=32/block: weight reuse beats occupancy — r6
// proved T=16 regresses) + gate fusion (3 GEMM phases -> 2) + register LN
// (r6's good part; sY LDS gone). 3 barriers, 35 KB LDS, grid 256.

typedef __bf16 bf16;
typedef __bf16 bf16x8 __attribute__((ext_vector_type(8)));
typedef __bf16 bf16x4 __attribute__((ext_vector_type(4)));
typedef float f32x4 __attribute__((ext_vector_type(4)));

#define NTOK 8192
#define D_   256
#define F_   32

// ws layout (bytes); total 416 KB (unchanged footprint)
#define OFF_C      512       // 256 f32: c[d]
#define OFF_BP     1536      // 256 f32: b' = gate_w@fc2_b + gate_b
#define OFF_WPROJT 4096      // WT[n][f] bf16 (fragment-coalesced), 16 KB
#define OFF_FC1    32768     // swizzled bf16, 128 KB each
#define OFF_FC2    163840
#define OFF_GF     294912    // swizzled bf16: GF = gate_w @ fc2_w

// Swizzled layout: elem = j*4096 + ks*512 + lm*32 + lq*8 + e
//   == W[row = j*16+lm][col = ks*32 + lq*8 + e]; a wave's (j,ks) fragment
// load is one contiguous 1 KB segment.

// ---- prep: blk 0..15 convert fc1/fc2; blk 16 softmax/WT/c; blk 17..80 GF ----
__global__ __launch_bounds__(256) void vsn_prep(
    const float* __restrict__ proj_w, const float* __restrict__ proj_b,
    const float* __restrict__ sc_ln_b,
    const float* __restrict__ fc1w, const float* __restrict__ fc2w,
    const float* __restrict__ fc2b,
    const float* __restrict__ gatew, const float* __restrict__ gateb,
    float* __restrict__ wsC, float* __restrict__ wsBp, bf16* __restrict__ wsWT,
    bf16* __restrict__ oFC1, bf16* __restrict__ oFC2, bf16* __restrict__ oGF)
{
  const int blk = blockIdx.x;
  if (blk < 16) {
    int g = blk * 256 + threadIdx.x;          // 0..4095
    int m = g >> 11;                          // 0=fc1, 1=fc2
    int c = g & 2047;                         // row = c>>3, ks = c&7
    const float* src = (m == 0) ? fc1w : fc2w;
    bf16* dst = (m == 0) ? oFC1 : oFC2;
    int row = c >> 3, ks = c & 7;
    int j = row >> 4, lm = row & 15;
    const float* sp = src + row * 256 + ks * 32;   // 32 contig floats
    bf16* dp = dst + j * 4096 + ks * 512 + lm * 32;
    #pragma unroll
    for (int q = 0; q < 4; q++) {
      float4 a = ((const float4*)sp)[2 * q];
      float4 b = ((const float4*)sp)[2 * q + 1];
      bf16x8 v = {(bf16)a.x, (bf16)a.y, (bf16)a.z, (bf16)a.w,
                  (bf16)b.x, (bf16)b.y, (bf16)b.z, (bf16)b.w};
      *(bf16x8*)(dp + q * 8) = v;
    }
  } else if (blk == 16) {
    const int d = threadIdx.x;
    float wv[F_];
    float mx = -3.0e38f;
    #pragma unroll
    for (int f = 0; f < F_; f++) { wv[f] = sc_ln_b[f]; mx = fmaxf(mx, wv[f]); }
    float se = 0.0f;
    #pragma unroll
    for (int f = 0; f < F_; f++) { wv[f] = __expf(wv[f] - mx); se += wv[f]; }
    float inv = 1.0f / se;
    float acc = 0.0f;
    #pragma unroll
    for (int f = 0; f < F_; f++) {
      float wf = wv[f] * inv;
      acc += wf * proj_b[f * D_ + d];
      wsWT[d * F_ + f] = (bf16)(wf * proj_w[f * D_ + d]);
    }
    wsC[d] = acc;
  } else {
    // GF rows rb..rb+3: GF = gate_w @ fc2_w (fp32 accumulate), b' rows too
    __shared__ float gs[4][257];
    const int rb = (blk - 17) * 4;
    const int c = threadIdx.x;
    #pragma unroll
    for (int r = 0; r < 4; r++) gs[r][c] = gatew[(rb + r) * 256 + c];
    __syncthreads();
    float a0 = 0.f, a1 = 0.f, a2 = 0.f, a3 = 0.f;
    for (int k = 0; k < 256; k++) {
      float f = fc2w[k * 256 + c];              // coalesced; gs[.][k] broadcast
      a0 += gs[0][k] * f;
      a1 += gs[1][k] * f;
      a2 += gs[2][k] * f;
      a3 += gs[3][k] * f;
    }
    float accr[4] = {a0, a1, a2, a3};
    #pragma unroll
    for (int r = 0; r < 4; r++) {
      int row = rb + r;
      oGF[(row >> 4) * 4096 + (c >> 5) * 512 + (row & 15) * 32 + (c & 31)] =
          (bf16)accr[r];
    }
    if (c < 4) {
      float s = gateb[rb + c];
      for (int k = 0; k < 256; k++) s += gs[c][k] * fc2b[k];
      wsBp[rb + c] = s;
    }
  }
}

// ---- main: 32 tokens / 4-wave block; wave w owns cols [64w, 64w+64) ----
__global__ __launch_bounds__(256, 1) void vsn_main(
    const float* __restrict__ x,
    const float* __restrict__ wsC,
    const bf16* __restrict__ WT,
    const bf16* __restrict__ FC1, const float* __restrict__ fc1_b,
    const bf16* __restrict__ FC2, const float* __restrict__ fc2_b,
    const bf16* __restrict__ GF, const float* __restrict__ bprime,
    const float* __restrict__ ln_g, const float* __restrict__ ln_b,
    float* __restrict__ out)
{
  __shared__ bf16  sAct[2][32][264];   // ping-pong bf16 activations (A operand)
  __shared__ float sLN[4][32][2];      // per-wave {sum, sumsq} per token row

  const int tid  = threadIdx.x;
  const int w    = tid >> 6;
  const int lane = tid & 63;
  const int lm   = lane & 15;
  const int lq   = lane >> 4;
  const int j0   = w * 4;
  const int tok0 = blockIdx.x * 32;

  // ---- phase 1: mix = x @ WT^T + c (K=32); 2 M-tiles share each B ----
  bf16x4 mixh[2][4];
  {
    bf16x8 a[2];
    #pragma unroll
    for (int t = 0; t < 2; t++) {
      const float* xp = x + (size_t)(tok0 + t * 16 + lm) * F_ + lq * 8;
      float4 x0 = *(const float4*)xp;
      float4 x1 = *(const float4*)(xp + 4);
      bf16x8 av = {(bf16)x0.x, (bf16)x0.y, (bf16)x0.z, (bf16)x0.w,
                   (bf16)x1.x, (bf16)x1.y, (bf16)x1.z, (bf16)x1.w};
      a[t] = av;
    }
    #pragma unroll
    for (int jj = 0; jj < 4; jj++) {
      int n = (j0 + jj) * 16 + lm;
      bf16x8 b = *(const bf16x8*)(WT + n * F_ + lq * 8);   // 1KB/wave contig
      float cv = wsC[n];
      #pragma unroll
      for (int t = 0; t < 2; t++) {
        f32x4 acc = {cv, cv, cv, cv};
        acc = __builtin_amdgcn_mfma_f32_16x16x32_bf16(a[t], b, acc, 0, 0, 0);
        bf16x4 mh = {(bf16)acc[0], (bf16)acc[1], (bf16)acc[2], (bf16)acc[3]};
        mixh[t][jj] = mh;
        #pragma unroll
        for (int r = 0; r < 4; r++) sAct[0][t * 16 + lq * 4 + r][n] = mh[r];
      }
    }
  }
  __syncthreads();

  // ---- phase 2: h1 = elu(mix @ fc1^T + b1) -> sAct[1] (double-buffered B) ----
  {
    bf16x8 af[2][8];
    #pragma unroll
    for (int t = 0; t < 2; t++)
      #pragma unroll
      for (int ks = 0; ks < 8; ks++)
        af[t][ks] = *(const bf16x8*)(&sAct[0][t * 16 + lm][ks * 32 + lq * 8]);
    const bf16* base = FC1 + j0 * 4096 + lm * 32 + lq * 8;
    bf16x8 bb[8];
    #pragma unroll
    for (int ks = 0; ks < 8; ks++)
      bb[ks] = *(const bf16x8*)(base + ks * 512);          // 1KB/wave contig
    #pragma unroll
    for (int jj = 0; jj < 4; jj++) {
      bf16x8 bn[8];
      if (jj < 3) {
        const bf16* nb = base + (jj + 1) * 4096;
        #pragma unroll
        for (int ks = 0; ks < 8; ks++)
          bn[ks] = *(const bf16x8*)(nb + ks * 512);
      }
      f32x4 acc0 = {0.f, 0.f, 0.f, 0.f}, acc1 = {0.f, 0.f, 0.f, 0.f};
      #pragma unroll
      for (int ks = 0; ks < 8; ks++) {
        acc0 = __builtin_amdgcn_mfma_f32_16x16x32_bf16(af[0][ks], bb[ks], acc0, 0, 0, 0);
        acc1 = __builtin_amdgcn_mfma_f32_16x16x32_bf16(af[1][ks], bb[ks], acc1, 0, 0, 0);
      }
      int n = (j0 + jj) * 16 + lm;
      float bias = fc1_b[n];
      #pragma unroll
      for (int r = 0; r < 4; r++) {
        float v0 = acc0[r] + bias;
        v0 = (v0 > 0.0f) ? v0 : (__expf(v0) - 1.0f);
        sAct[1][lq * 4 + r][n] = (bf16)v0;
        float v1 = acc1[r] + bias;
        v1 = (v1 > 0.0f) ? v1 : (__expf(v1) - 1.0f);
        sAct[1][16 + lq * 4 + r][n] = (bf16)v1;
      }
      if (jj < 3) {
        #pragma unroll
        for (int ks = 0; ks < 8; ks++) bb[ks] = bn[ks];
      }
    }
  }
  __syncthreads();

  // ---- phase 3 (fused): h2 = h1@fc2^T + b2 ; glog = h1@GF^T + b' ;
  //      g = sigmoid(glog) ; y2 = g*h2 + (1-g)*mix  (all in registers) ----
  f32x4 y2[2][4];
  {
    bf16x8 af[2][8];
    #pragma unroll
    for (int t = 0; t < 2; t++)
      #pragma unroll
      for (int ks = 0; ks < 8; ks++)
        af[t][ks] = *(const bf16x8*)(&sAct[1][t * 16 + lm][ks * 32 + lq * 8]);
    const bf16* baseF = FC2 + j0 * 4096 + lm * 32 + lq * 8;
    const bf16* baseG = GF  + j0 * 4096 + lm * 32 + lq * 8;
    #pragma unroll
    for (int jj = 0; jj < 4; jj++) {
      bf16x8 bF[8], bG[8];                    // 16 outstanding loads
      #pragma unroll
      for (int ks = 0; ks < 8; ks++) {
        bF[ks] = *(const bf16x8*)(baseF + jj * 4096 + ks * 512);
        bG[ks] = *(const bf16x8*)(baseG + jj * 4096 + ks * 512);
      }
      f32x4 hF0 = {0.f,0.f,0.f,0.f}, hF1 = {0.f,0.f,0.f,0.f};
      f32x4 hG0 = {0.f,0.f,0.f,0.f}, hG1 = {0.f,0.f,0.f,0.f};
      #pragma unroll
      for (int ks = 0; ks < 8; ks++) {        // 4 independent MFMA chains
        hF0 = __builtin_amdgcn_mfma_f32_16x16x32_bf16(af[0][ks], bF[ks], hF0, 0, 0, 0);
        hF1 = __builtin_amdgcn_mfma_f32_16x16x32_bf16(af[1][ks], bF[ks], hF1, 0, 0, 0);
        hG0 = __builtin_amdgcn_mfma_f32_16x16x32_bf16(af[0][ks], bG[ks], hG0, 0, 0, 0);
        hG1 = __builtin_amdgcn_mfma_f32_16x16x32_bf16(af[1][ks], bG[ks], hG1, 0, 0, 0);
      }
      int n = (j0 + jj) * 16 + lm;
      float b2v = fc2_b[n];
      float bpv = bprime[n];
      #pragma unroll
      for (int r = 0; r < 4; r++) {
        float h20 = hF0[r] + b2v;
        float g0  = 1.0f / (1.0f + __expf(-(hG0[r] + bpv)));
        y2[0][jj][r] = g0 * h20 + (1.0f - g0) * (float)mixh[0][jj][r];
        float h21 = hF1[r] + b2v;
        float g1  = 1.0f / (1.0f + __expf(-(hG1[r] + bpv)));
        y2[1][jj][r] = g1 * h21 + (1.0f - g1) * (float)mixh[1][jj][r];
      }
    }
  }

  // ---- LayerNorm(256) via cross-wave partial sums ----
  #pragma unroll
  for (int t = 0; t < 2; t++) {
    float rs[4] = {0.f,0.f,0.f,0.f}, rq[4] = {0.f,0.f,0.f,0.f};
    #pragma unroll
    for (int jj = 0; jj < 4; jj++)
      #pragma unroll
      for (int r = 0; r < 4; r++) {
        float y = y2[t][jj][r];
        rs[r] += y;
        rq[r] += y * y;
      }
    #pragma unroll
    for (int r = 0; r < 4; r++) {
      #pragma unroll
      for (int off = 1; off < 16; off <<= 1) {
        rs[r] += __shfl_xor(rs[r], off);
        rq[r] += __shfl_xor(rq[r], off);
      }
      if (lm == 0) {
        sLN[w][t * 16 + lq * 4 + r][0] = rs[r];
        sLN[w][t * 16 + lq * 4 + r][1] = rq[r];
      }
    }
  }
  __syncthreads();

  const float inv_d = 1.0f / 256.0f;
  #pragma unroll
  for (int t = 0; t < 2; t++) {
    float mean[4], rstd[4];
    #pragma unroll
    for (int r = 0; r < 4; r++) {
      int row = t * 16 + lq * 4 + r;
      float S = sLN[0][row][0] + sLN[1][row][0] + sLN[2][row][0] + sLN[3][row][0];
      float Q = sLN[0][row][1] + sLN[1][row][1] + sLN[2][row][1] + sLN[3][row][1];
      float m = S * inv_d;
      mean[r] = m;
      rstd[r] = rsqrtf(Q * inv_d - m * m + 1e-5f);
    }
    #pragma unroll
    for (int jj = 0; jj < 4; jj++) {
      int n = (j0 + jj) * 16 + lm;
      float lg = ln_g[n], lb = ln_b[n];
      #pragma unroll
      for (int r = 0; r < 4; r++) {
        float o = (y2[t][jj][r] - mean[r]) * rstd[r] * lg + lb;
        out[(size_t)(tok0 + t * 16 + lq * 4 + r) * D_ + n] = o;
      }
    }
  }
}

extern "C" void kernel_launch(void* const* d_in, const int* in_sizes, int n_in,
                              void* d_out, int out_size, void* d_ws, size_t ws_size,
                              hipStream_t stream) {
  (void)in_sizes; (void)n_in; (void)ws_size; (void)out_size;
  const float* x      = (const float*)d_in[0];
  const float* proj_w = (const float*)d_in[1];
  const float* proj_b = (const float*)d_in[2];
  const float* sclnb  = (const float*)d_in[12];
  const float* fc1w   = (const float*)d_in[13];
  const float* fc1b   = (const float*)d_in[14];
  const float* fc2w   = (const float*)d_in[15];
  const float* fc2b   = (const float*)d_in[16];
  const float* gw     = (const float*)d_in[17];
  const float* gb     = (const float*)d_in[18];
  const float* lng    = (const float*)d_in[19];
  const float* lnb    = (const float*)d_in[20];

  char* ws = (char*)d_ws;
  float* wsC   = (float*)(ws + OFF_C);
  float* wsBp  = (float*)(ws + OFF_BP);
  bf16*  wsWT  = (bf16*)(ws + OFF_WPROJT);
  bf16*  bFC1  = (bf16*)(ws + OFF_FC1);
  bf16*  bFC2  = (bf16*)(ws + OFF_FC2);
  bf16*  bGF   = (bf16*)(ws + OFF_GF);

  vsn_prep<<<81, 256, 0, stream>>>(proj_w, proj_b, sclnb, fc1w, fc2w, fc2b,
                                   gw, gb, wsC, wsBp, wsWT, bFC1, bFC2, bGF);
  vsn_main<<<NTOK / 32, 256, 0, stream>>>(x, wsC, wsWT,
                                          bFC1, fc1b, bFC2, fc2b, bGF, wsBp,
                                          lng, lnb, (float*)d_out);
}

// Round 8
// 115.004 us; speedup vs baseline: 1.1336x; 1.1336x over previous
//
#include <hip/hip_runtime.h>
#include <hip/hip_bf16.h>
#include <math.h>

// VariableSelectionNetwork — MI355X (gfx950), round 8
//
// Identity: scorer LayerNorm over a size-1 axis => output == sc_ln_b, so
// softmax weights W[f] = softmax(sc_ln_b) are constant and the scorer GRN is
// dead code. Remaining: mix = x @ WT^T + c ; post-GRN (3x 256x256) ; gated
// skip ; LayerNorm(256).
//
// Round 8 = round-5 winner (T=32/block, swizzled weights, 3 GEMM phases —
// r7's fused-gate prep GEMM was a serial-latency own-goal, reverted) +
// register LayerNorm (r6's good part) + NEW: 512-thread blocks (8 waves,
// 2 n-tiles/wave). Same weight traffic per block (weight-broadcast-bound,
// r6 proved smaller T regresses) but 2 waves/SIMD instead of 1 -> latency
// waits of one wave overlap the other's MFMAs.

typedef __bf16 bf16;
typedef __bf16 bf16x8 __attribute__((ext_vector_type(8)));
typedef __bf16 bf16x4 __attribute__((ext_vector_type(4)));
typedef float f32x4 __attribute__((ext_vector_type(4)));

#define NTOK 8192
#define D_   256
#define F_   32

// ws layout (bytes)
#define OFF_C      512       // 256 f32
#define OFF_WPROJT 2048      // WT[n][f] bf16 (fragment-coalesced), 16 KB
#define OFF_FC1    32768     // swizzled bf16, 128 KB each
#define OFF_FC2    163840
#define OFF_GATE   294912

// Swizzled layout: elem = j*4096 + ks*512 + lm*32 + lq*8 + e
//   == W[row = j*16+lm][col = ks*32 + lq*8 + e]; a wave's (j,ks) fragment
// load is one contiguous 1 KB segment.

// ---- prep: blocks 0..23 swizzle-convert 3 weights; block 24 softmax/WT/c ----
__global__ __launch_bounds__(256) void vsn_prep(
    const float* __restrict__ proj_w, const float* __restrict__ proj_b,
    const float* __restrict__ sc_ln_b,
    const float* __restrict__ w1, const float* __restrict__ w2,
    const float* __restrict__ w3,
    float* __restrict__ wsC, bf16* __restrict__ wsWT,
    bf16* __restrict__ o1, bf16* __restrict__ o2, bf16* __restrict__ o3)
{
  const int blk = blockIdx.x;
  if (blk < 24) {
    int g = blk * 256 + threadIdx.x;          // 0..6143
    int m = g >> 11;                          // matrix 0..2
    int c = g & 2047;                         // row = c>>3, ks = c&7
    const float* src = (m == 0) ? w1 : (m == 1) ? w2 : w3;
    bf16* dst = (m == 0) ? o1 : (m == 1) ? o2 : o3;
    int row = c >> 3, ks = c & 7;
    int j = row >> 4, lm = row & 15;
    const float* sp = src + row * 256 + ks * 32;   // 32 contig floats
    bf16* dp = dst + j * 4096 + ks * 512 + lm * 32;
    #pragma unroll
    for (int q = 0; q < 4; q++) {
      float4 a = ((const float4*)sp)[2 * q];
      float4 b = ((const float4*)sp)[2 * q + 1];
      bf16x8 v = {(bf16)a.x, (bf16)a.y, (bf16)a.z, (bf16)a.w,
                  (bf16)b.x, (bf16)b.y, (bf16)b.z, (bf16)b.w};
      *(bf16x8*)(dp + q * 8) = v;
    }
  } else {
    const int d = threadIdx.x;
    float wv[F_];
    float mx = -3.0e38f;
    #pragma unroll
    for (int f = 0; f < F_; f++) { wv[f] = sc_ln_b[f]; mx = fmaxf(mx, wv[f]); }
    float se = 0.0f;
    #pragma unroll
    for (int f = 0; f < F_; f++) { wv[f] = __expf(wv[f] - mx); se += wv[f]; }
    float inv = 1.0f / se;
    float acc = 0.0f;
    #pragma unroll
    for (int f = 0; f < F_; f++) {
      float wf = wv[f] * inv;
      acc += wf * proj_b[f * D_ + d];
      wsWT[d * F_ + f] = (bf16)(wf * proj_w[f * D_ + d]);
    }
    wsC[d] = acc;
  }
}

// ---- main: 32 tokens / 8-wave block; wave w owns cols [32w, 32w+32) ----
__global__ __launch_bounds__(512, 1) void vsn_main(
    const float* __restrict__ x,
    const float* __restrict__ wsC,
    const bf16* __restrict__ WT,
    const bf16* __restrict__ FC1, const float* __restrict__ fc1_b,
    const bf16* __restrict__ FC2, const float* __restrict__ fc2_b,
    const bf16* __restrict__ GATE, const float* __restrict__ gate_b,
    const float* __restrict__ ln_g, const float* __restrict__ ln_b,
    float* __restrict__ out)
{
  __shared__ bf16  sAct[2][32][264];   // ping-pong bf16 activations (A operand)
  __shared__ float sLN[8][32][2];      // per-wave {sum, sumsq} per token row

  const int tid  = threadIdx.x;
  const int w    = tid >> 6;           // wave 0..7
  const int lane = tid & 63;
  const int lm   = lane & 15;
  const int lq   = lane >> 4;
  const int j0   = w * 2;              // this wave's 2 n-tiles
  const int tok0 = blockIdx.x * 32;

  // ---- phase 1: mix = x @ WT^T + c (K=32); 2 M-tiles share each B ----
  bf16x4 mixh[2][2];                   // [t][jj]
  {
    bf16x8 a[2];
    #pragma unroll
    for (int t = 0; t < 2; t++) {
      const float* xp = x + (size_t)(tok0 + t * 16 + lm) * F_ + lq * 8;
      float4 x0 = *(const float4*)xp;
      float4 x1 = *(const float4*)(xp + 4);
      bf16x8 av = {(bf16)x0.x, (bf16)x0.y, (bf16)x0.z, (bf16)x0.w,
                   (bf16)x1.x, (bf16)x1.y, (bf16)x1.z, (bf16)x1.w};
      a[t] = av;
    }
    #pragma unroll
    for (int jj = 0; jj < 2; jj++) {
      int n = (j0 + jj) * 16 + lm;
      bf16x8 b = *(const bf16x8*)(WT + n * F_ + lq * 8);   // 1KB/wave contig
      float cv = wsC[n];
      #pragma unroll
      for (int t = 0; t < 2; t++) {
        f32x4 acc = {cv, cv, cv, cv};
        acc = __builtin_amdgcn_mfma_f32_16x16x32_bf16(a[t], b, acc, 0, 0, 0);
        bf16x4 mh = {(bf16)acc[0], (bf16)acc[1], (bf16)acc[2], (bf16)acc[3]};
        mixh[t][jj] = mh;
        #pragma unroll
        for (int r = 0; r < 4; r++) sAct[0][t * 16 + lq * 4 + r][n] = mh[r];
      }
    }
  }
  __syncthreads();

  // [32,256] @ W^T on this wave's 2 n-tiles; swizzled B, double-buffered
  auto gemmPhase = [&](int src, const bf16* __restrict__ W, f32x4 (*acc)[2]) {
    bf16x8 af[2][8];
    #pragma unroll
    for (int t = 0; t < 2; t++)
      #pragma unroll
      for (int ks = 0; ks < 8; ks++)
        af[t][ks] = *(const bf16x8*)(&sAct[src][t * 16 + lm][ks * 32 + lq * 8]);
    const bf16* base = W + j0 * 4096 + lm * 32 + lq * 8;
    bf16x8 bb[8], bn[8];
    #pragma unroll
    for (int ks = 0; ks < 8; ks++)
      bb[ks] = *(const bf16x8*)(base + ks * 512);          // 1KB/wave contig
    #pragma unroll
    for (int ks = 0; ks < 8; ks++)
      bn[ks] = *(const bf16x8*)(base + 4096 + ks * 512);
    #pragma unroll
    for (int jj = 0; jj < 2; jj++) {
      f32x4 a0 = {0.f, 0.f, 0.f, 0.f}, a1 = {0.f, 0.f, 0.f, 0.f};
      #pragma unroll
      for (int ks = 0; ks < 8; ks++) {
        const bf16x8 bv = (jj == 0) ? bb[ks] : bn[ks];
        a0 = __builtin_amdgcn_mfma_f32_16x16x32_bf16(af[0][ks], bv, a0, 0, 0, 0);
        a1 = __builtin_amdgcn_mfma_f32_16x16x32_bf16(af[1][ks], bv, a1, 0, 0, 0);
      }
      acc[0][jj] = a0;
      acc[1][jj] = a1;
    }
  };

  // ---- phase 2: h1 = elu(mix @ fc1^T + b1) -> sAct[1] ----
  {
    f32x4 acc[2][2];
    gemmPhase(0, FC1, acc);
    #pragma unroll
    for (int jj = 0; jj < 2; jj++) {
      int n = (j0 + jj) * 16 + lm;
      float bias = fc1_b[n];
      #pragma unroll
      for (int t = 0; t < 2; t++)
        #pragma unroll
        for (int r = 0; r < 4; r++) {
          float v = acc[t][jj][r] + bias;
          v = (v > 0.0f) ? v : (__expf(v) - 1.0f);
          sAct[1][t * 16 + lq * 4 + r][n] = (bf16)v;
        }
    }
  }
  __syncthreads();

  // ---- phase 3: h2 = h1 @ fc2^T + b2 -> sAct[0], keep packed regs ----
  bf16x4 h2h[2][2];
  {
    f32x4 acc[2][2];
    gemmPhase(1, FC2, acc);
    #pragma unroll
    for (int jj = 0; jj < 2; jj++) {
      int n = (j0 + jj) * 16 + lm;
      float bias = fc2_b[n];
      #pragma unroll
      for (int t = 0; t < 2; t++) {
        bf16x4 hh;
        #pragma unroll
        for (int r = 0; r < 4; r++) {
          hh[r] = (bf16)(acc[t][jj][r] + bias);
          sAct[0][t * 16 + lq * 4 + r][n] = hh[r];
        }
        h2h[t][jj] = hh;
      }
    }
  }
  __syncthreads();

  // ---- phase 4: gate, gated skip; y2 stays in registers ----
  f32x4 y2[2][2];
  {
    f32x4 acc[2][2];
    gemmPhase(0, GATE, acc);
    #pragma unroll
    for (int jj = 0; jj < 2; jj++) {
      int n = (j0 + jj) * 16 + lm;
      float bias = gate_b[n];
      #pragma unroll
      for (int t = 0; t < 2; t++)
        #pragma unroll
        for (int r = 0; r < 4; r++) {
          float s = acc[t][jj][r] + bias;
          float g = 1.0f / (1.0f + __expf(-s));
          y2[t][jj][r] = g * (float)h2h[t][jj][r] +
                         (1.0f - g) * (float)mixh[t][jj][r];
        }
    }
  }

  // ---- phase 5: LayerNorm(256) via cross-wave partial sums ----
  #pragma unroll
  for (int t = 0; t < 2; t++) {
    float rs[4] = {0.f, 0.f, 0.f, 0.f}, rq[4] = {0.f, 0.f, 0.f, 0.f};
    #pragma unroll
    for (int jj = 0; jj < 2; jj++)
      #pragma unroll
      for (int r = 0; r < 4; r++) {
        float y = y2[t][jj][r];
        rs[r] += y;
        rq[r] += y * y;
      }
    #pragma unroll
    for (int r = 0; r < 4; r++) {
      #pragma unroll
      for (int off = 1; off < 16; off <<= 1) {
        rs[r] += __shfl_xor(rs[r], off);
        rq[r] += __shfl_xor(rq[r], off);
      }
      if (lm == 0) {
        sLN[w][t * 16 + lq * 4 + r][0] = rs[r];
        sLN[w][t * 16 + lq * 4 + r][1] = rq[r];
      }
    }
  }
  __syncthreads();

  const float inv_d = 1.0f / 256.0f;
  #pragma unroll
  for (int t = 0; t < 2; t++) {
    float mean[4], rstd[4];
    #pragma unroll
    for (int r = 0; r < 4; r++) {
      int row = t * 16 + lq * 4 + r;
      float S = 0.f, Q = 0.f;
      #pragma unroll
      for (int wv = 0; wv < 8; wv++) {
        S += sLN[wv][row][0];
        Q += sLN[wv][row][1];
      }
      float m = S * inv_d;
      mean[r] = m;
      rstd[r] = rsqrtf(Q * inv_d - m * m + 1e-5f);
    }
    #pragma unroll
    for (int jj = 0; jj < 2; jj++) {
      int n = (j0 + jj) * 16 + lm;
      float lg = ln_g[n], lb = ln_b[n];
      #pragma unroll
      for (int r = 0; r < 4; r++) {
        float o = (y2[t][jj][r] - mean[r]) * rstd[r] * lg + lb;
        out[(size_t)(tok0 + t * 16 + lq * 4 + r) * D_ + n] = o;
      }
    }
  }
}

extern "C" void kernel_launch(void* const* d_in, const int* in_sizes, int n_in,
                              void* d_out, int out_size, void* d_ws, size_t ws_size,
                              hipStream_t stream) {
  (void)in_sizes; (void)n_in; (void)ws_size; (void)out_size;
  const float* x      = (const float*)d_in[0];
  const float* proj_w = (const float*)d_in[1];
  const float* proj_b = (const float*)d_in[2];
  const float* sclnb  = (const float*)d_in[12];
  const float* fc1w   = (const float*)d_in[13];
  const float* fc1b   = (const float*)d_in[14];
  const float* fc2w   = (const float*)d_in[15];
  const float* fc2b   = (const float*)d_in[16];
  const float* gw     = (const float*)d_in[17];
  const float* gb     = (const float*)d_in[18];
  const float* lng    = (const float*)d_in[19];
  const float* lnb    = (const float*)d_in[20];

  char* ws = (char*)d_ws;
  float* wsC   = (float*)(ws + OFF_C);
  bf16*  wsWT  = (bf16*)(ws + OFF_WPROJT);
  bf16*  bFC1  = (bf16*)(ws + OFF_FC1);
  bf16*  bFC2  = (bf16*)(ws + OFF_FC2);
  bf16*  bGATE = (bf16*)(ws + OFF_GATE);

  vsn_prep<<<25, 256, 0, stream>>>(proj_w, proj_b, sclnb, fc1w, fc2w, gw,
                                   wsC, wsWT, bFC1, bFC2, bGATE);
  vsn_main<<<NTOK / 32, 512, 0, stream>>>(x, wsC, wsWT,
                                          bFC1, fc1b, bFC2, fc2b, bGATE, gb,
                                          lng, lnb, (float*)d_out);
}